// Round 15
// baseline (167.092 us; speedup 1.0000x reference)
//
#include <hip/hip_runtime.h>
#include <math.h>

// Problem constants: B=16, N=M=4096, K=64.
#define BB 16
#define NN 4096
#define MM 4096
#define NSLICE 2
#define SLICE_COLS 2048               // cols per block
#define NJT (SLICE_COLS / 64)         // 32
#define ROWS_PER_BLOCK 256            // 8 waves x 32 rows
#define NCHAMFER 512                  // 16 tiles * 2 slices * 16 b
#define WSCOL_OFF (BB * NSLICE * NN)  // 131072 floats; then u32 col planes
#define CTR_BYTE_OFF (3u << 20)       // barrier counter, past all ws usage (2.62MB)

typedef __attribute__((ext_vector_type(8))) short bf16x8;
typedef __attribute__((ext_vector_type(16))) float f32x16;

static __device__ inline unsigned short f2bf(float f) {
    unsigned int u = __float_as_uint(f);
    return (unsigned short)((u + 0x7FFFu + ((u >> 16) & 1u)) >> 16);  // RNE
}
static __device__ inline bf16x8 bzero() {
    bf16x8 z;
    #pragma unroll
    for (int i = 0; i < 8; ++i) z[i] = 0;
    return z;
}
static __device__ inline f32x16 fzero16() {
    f32x16 z;
    #pragma unroll
    for (int i = 0; i < 16; ++i) z[i] = 0.f;
    return z;
}
static __device__ inline float min3f(float a, float b, float c) {
    return fminf(fminf(a, b), c);     // v_min3_f32
}
// min over one f32x16 via min3 tree: 8 ops.
static __device__ inline float tree16(const f32x16 x) {
    const float p0 = min3f(x[0], x[1], x[2]);
    const float p1 = min3f(x[3], x[4], x[5]);
    const float p2 = min3f(x[6], x[7], x[8]);
    const float p3 = min3f(x[9], x[10], x[11]);
    const float p4 = min3f(x[12], x[13], x[14]);
    const float q0 = min3f(p0, p1, x[15]);
    const float q1 = min3f(p2, p3, p4);
    return fminf(q0, q1);
}

#define MFMA32(Af, Bf, Cf) __builtin_amdgcn_mfma_f32_32x32x16_bf16(Af, Bf, Cf, 0, 0, 0)

// ---------------------------------------------------------------------------
// ONE main dispatch. Phase 1 = R13 chamfer (one D-matrix, both reductions,
// 8 waves x 32 rows, bf16-pair col planes). In-kernel global barrier:
// counter zeroed by a preceding 4-byte memsetAsync; grid (512 blocks, 64KB
// LDS) is EXACTLY the co-residency capacity (2/CU x 256), so spinning is
// deadlock-free. Phase 2 = distributed finish (128 rows / 64 cols / 16 reg
// blocks). No second kernel launch.
// ---------------------------------------------------------------------------
__global__ __launch_bounds__(512, 4) void fused_loss_kernel(
    const float* __restrict__ pred, const float* __restrict__ gt,
    const float* __restrict__ trans, float* __restrict__ ws,
    unsigned* __restrict__ ctr, float* __restrict__ out)
{
    const int bx  = blockIdx.x;
    const int tid = threadIdx.x;
    if (bx == 0 && tid == 0) *out = 0.0f;   // ordered before all adds by barrier

    __shared__ __align__(16) unsigned char lds[65536];
    uint4* sB = (uint4*)lds;                          // [0, 32768)
    const bf16x8* sBf = (const bf16x8*)lds;
    unsigned* colw = (unsigned*)(lds + 32768);        // [32768, 65536): 8 x 1024 u32
    float* epi = (float*)lds;                         // row-epi reuse

    const int lane = tid & 63;
    const int w    = tid >> 6;                        // wave 0..7
    const int li   = lane & 31;
    const int hi   = lane >> 5;
    const int tile   = bx & 15;
    const int mslice = (bx >> 4) & 1;
    const int b      = bx >> 5;
    const float* rb = pred + (size_t)b * NN * 3;
    const float* cb = gt + ((size_t)b * MM + (size_t)mslice * SLICE_COLS) * 3;

    // A-frag: 32 rows (rbase+li). Lanes 0-31 carry k=0..7 (k0..4); 32-63 zero.
    const int rbase = tile * ROWS_PER_BLOCK + w * 32;
    bf16x8 A0 = bzero();
    if (lane < 32) {
        const float* rp = rb + (size_t)(rbase + li) * 3;
        const float px = rp[0], py = rp[1], pz = rp[2];
        const float p2 = px * px + py * py + pz * pz;
        bf16x8 fr = bzero();
        fr[0] = (short)f2bf(-2.f * px);
        fr[1] = (short)f2bf(-2.f * py);
        fr[2] = (short)f2bf(-2.f * pz);
        fr[3] = (short)f2bf(p2);
        fr[4] = (short)0x3F80;              // 1.0
        A0 = fr;
    }

    // Stage gt slice: packed bf16x8 per col = (t,1,t2,0,0,0). 2 col-pairs/thread.
    #pragma unroll
    for (int i = 0; i < 2; ++i) {
        const int c0 = (i * 512 + tid) * 2;
        const float2* sp = (const float2*)(cb + (size_t)c0 * 3);
        const float2 v0 = sp[0], v1 = sp[1], v2 = sp[2];
        const float t2a = v0.x * v0.x + v0.y * v0.y + v1.x * v1.x;
        const float t2b = v1.y * v1.y + v2.x * v2.x + v2.y * v2.y;
        uint4 pa, pb;
        pa.x = (unsigned)f2bf(v0.x) | ((unsigned)f2bf(v0.y) << 16);
        pa.y = (unsigned)f2bf(v1.x) | (0x3F80u << 16);
        pa.z = (unsigned)f2bf(t2a);
        pa.w = 0u;
        pb.x = (unsigned)f2bf(v1.y) | ((unsigned)f2bf(v2.x) << 16);
        pb.y = (unsigned)f2bf(v2.y) | (0x3F80u << 16);
        pb.z = (unsigned)f2bf(t2b);
        pb.w = 0u;
        sB[c0]     = pa;
        sB[c0 + 1] = pb;
    }
    __syncthreads();

    float mv[16];
    #pragma unroll
    for (int r = 0; r < 16; ++r) mv[r] = 3.4e38f;

    const f32x16 Z = fzero16();
    unsigned* myplane = colw + w * 1024;

    bf16x8 c1 = sBf[li], c2 = sBf[32 + li];   // lanes>=32 dup-read (A=0 there)
    #pragma unroll 2
    for (int jt = 0; jt < NJT; ++jt) {
        bf16x8 n1 = c1, n2 = c2;
        if (jt + 1 < NJT) {
            n1 = sBf[(jt + 1) * 64 + li];
            n2 = sBf[(jt + 1) * 64 + 32 + li];
        }
        f32x16 a0 = MFMA32(A0, c1, Z);        // col group li
        f32x16 a1 = MFMA32(A0, c2, Z);        // col group 32+li
        #pragma unroll
        for (int r = 0; r < 16; ++r)
            mv[r] = min3f(a0[r], a1[r], mv[r]);
        float tA = tree16(a0);
        float tB = tree16(a1);
        tA = fminf(tA, __shfl_xor(tA, 32, 64));
        tB = fminf(tB, __shfl_xor(tB, 32, 64));
        unsigned pk;
        asm("v_cvt_pk_bf16_f32 %0, %1, %2" : "=v"(pk) : "v"(tA), "v"(tB));
        if (lane < 32) myplane[jt * 32 + li] = pk;
        c1 = n1; c2 = n2;
    }
    __syncthreads();                          // colw complete

    // Col epilogue: umin across 8 planes per u16 half, coalesced u32 ws store.
    {
        unsigned* wc = (unsigned*)(ws + WSCOL_OFF)
                     + (((size_t)b * 16 + tile) * NSLICE + mslice) * 1024;
        #pragma unroll
        for (int i = 0; i < 2; ++i) {
            const int slot = i * 512 + tid;
            unsigned la = 0xFFFFu, ha = 0xFFFFu;
            #pragma unroll
            for (int p = 0; p < 8; ++p) {
                const unsigned u = colw[p * 1024 + slot];
                la = min(la, u & 0xFFFFu);
                ha = min(ha, u >> 16);
            }
            wc[slot] = la | (ha << 16);
        }
    }
    __syncthreads();                          // colw free; row transpose begins

    // Row epilogue: transpose mv via LDS [wave][li][row_local], stride 36.
    {
        float* wb = epi + w * 1152 + li * 36;
        #pragma unroll
        for (int q = 0; q < 4; ++q)
            *(float4*)&wb[q * 8 + hi * 4] =
                make_float4(mv[4*q], mv[4*q+1], mv[4*q+2], mv[4*q+3]);
    }
    __syncthreads();

    if (tid < ROWS_PER_BLOCK) {
        const int wsrc = tid >> 5, rl = tid & 31;
        const float* rr = epi + wsrc * 1152 + rl;
        float m = 3.4e38f;
        #pragma unroll
        for (int c = 0; c < 32; c += 2) m = min3f(rr[c * 36], rr[(c + 1) * 36], m);
        ws[((size_t)b * NSLICE + mslice) * NN + tile * ROWS_PER_BLOCK + tid] = m;
    }

    // =================== global barrier (counter pre-zeroed) ===================
    __threadfence();                          // each thread's ws stores visible
    __syncthreads();
    if (tid == 0) {
        atomicAdd(ctr, 1u);                   // device-scope arrive
        while (__hip_atomic_load(ctr, __ATOMIC_ACQUIRE,
                                 __HIP_MEMORY_SCOPE_AGENT) < NCHAMFER) {
            __builtin_amdgcn_s_sleep(1);
        }
    }
    __syncthreads();
    __threadfence();

    // =================== Phase 2: distributed finish ===================
    float* ssum = (float*)lds;                // LDS reuse for block reduce

    if (bx < 128) {
        // rows: 128 blocks x 512 threads = 65536 = one thread per (b,n)
        const int g = bx * 512 + tid;
        const int rb2 = g >> 12, n = g & (NN - 1);
        const float* p0 = ws + ((size_t)rb2 * NSLICE) * NN;
        const float v = fminf(p0[n], p0[NN + n]);
        float s = sqrtf(fmaxf(v, 0.0f));
        #pragma unroll
        for (int off = 32; off > 0; off >>= 1)
            s += __shfl_down(s, off, 64);
        if (lane == 0) ssum[w] = s;
        __syncthreads();
        if (tid == 0) {
            float t = 0.f;
            #pragma unroll
            for (int i = 0; i < 8; ++i) t += ssum[i];
            atomicAdd(out, t * (1.0f / ((float)BB * (float)NN)));
        }
    } else if (bx < 192) {
        // cols: 64 blocks x 512 threads = 32768 u32 slots (2 cols each)
        const int g = (bx - 128) * 512 + tid;           // 0..32767
        const int cb2 = g >> 11;                        // batch
        const int rest = g & 2047;
        const int sl = rest >> 10, slot = rest & 1023;
        const unsigned* base = (const unsigned*)(ws + WSCOL_OFF)
                             + (size_t)cb2 * 16 * NSLICE * 1024;
        unsigned la = 0xFFFFu, ha = 0xFFFFu;
        #pragma unroll
        for (int t = 0; t < 16; ++t) {
            const unsigned u = base[((size_t)t * NSLICE + sl) * 1024 + slot];
            la = min(la, u & 0xFFFFu);
            ha = min(ha, u >> 16);
        }
        float s = sqrtf(fmaxf(__uint_as_float(la << 16), 0.0f))
                + sqrtf(fmaxf(__uint_as_float(ha << 16), 0.0f));
        #pragma unroll
        for (int off = 32; off > 0; off >>= 1)
            s += __shfl_down(s, off, 64);
        if (lane == 0) ssum[w] = s;
        __syncthreads();
        if (tid == 0) {
            float t = 0.f;
            #pragma unroll
            for (int i = 0; i < 8; ++i) t += ssum[i];
            atomicAdd(out, t * (1.0f / ((float)BB * (float)NN)));
        }
    } else if (bx < 208 && tid < 64) {
        // regularizer: 16 blocks, one wave each
        const int rb3 = bx - 192;
        const int rhi = tid >> 5, rli = tid & 31;
        const float* T = trans + (size_t)rb3 * 64 * 64;
        bf16x8 frag[2][4];
        #pragma unroll
        for (int h = 0; h < 2; ++h)
            #pragma unroll
            for (int s = 0; s < 4; ++s) {
                const float* rp = T + (size_t)(h * 32 + rli) * 64 + s * 16 + rhi * 8;
                const float4 u0 = *(const float4*)rp;
                const float4 u1 = *(const float4*)(rp + 4);
                bf16x8 fr;
                fr[0] = (short)f2bf(u0.x); fr[1] = (short)f2bf(u0.y);
                fr[2] = (short)f2bf(u0.z); fr[3] = (short)f2bf(u0.w);
                fr[4] = (short)f2bf(u1.x); fr[5] = (short)f2bf(u1.y);
                fr[6] = (short)f2bf(u1.z); fr[7] = (short)f2bf(u1.w);
                frag[h][s] = fr;
            }
        float fsum = 0.f;
        #pragma unroll
        for (int fi = 0; fi < 2; ++fi)
            #pragma unroll
            for (int fj = 0; fj < 2; ++fj) {
                f32x16 a = fzero16();
                #pragma unroll
                for (int s = 0; s < 4; ++s)
                    a = MFMA32(frag[fi][s], frag[fj][s], a);
                #pragma unroll
                for (int r = 0; r < 16; ++r) {
                    const int row = fi * 32 + (r & 3) + 8 * (r >> 2) + 4 * rhi;
                    const int col = fj * 32 + rli;
                    const float d = a[r] - ((row == col) ? 1.0f : 0.0f);
                    fsum = fmaf(d, d, fsum);
                }
            }
        #pragma unroll
        for (int off = 32; off > 0; off >>= 1)
            fsum += __shfl_down(fsum, off, 64);
        if (tid == 0)
            atomicAdd(out, (0.1f / (float)BB) * sqrtf(fsum));
    }
}

extern "C" void kernel_launch(void* const* d_in, const int* in_sizes, int n_in,
                              void* d_out, int out_size, void* d_ws, size_t ws_size,
                              hipStream_t stream)
{
    const float* pred  = (const float*)d_in[0];
    const float* gt    = (const float*)d_in[1];
    const float* trans = (const float*)d_in[2];
    float* out = (float*)d_out;
    float* ws = (float*)d_ws;
    unsigned* ctr = (unsigned*)((char*)d_ws + CTR_BYTE_OFF);

    hipMemsetAsync(ctr, 0, sizeof(unsigned), stream);   // barrier counter = 0
    fused_loss_kernel<<<dim3(NCHAMFER), dim3(512), 0, stream>>>(
        pred, gt, trans, ws, ctr, out);
}

// Round 16
// 28.276 us; speedup vs baseline: 5.9093x; 5.9093x over previous
//
#include <hip/hip_runtime.h>
#include <math.h>

// Problem constants: B=16, N=M=4096, K=64.
#define BB 16
#define NN 4096
#define MM 4096
#define NSLICE 2
#define SLICE_COLS 2048               // cols per block
#define NJT (SLICE_COLS / 64)         // 32
#define ROWS_PER_BLOCK 256            // 8 waves x 32 rows
#define NCHAMFER 512                  // 16 tiles * 2 slices * 16 b
#define WSCOL_OFF (BB * NSLICE * NN)  // 131072 floats; then u32 col planes
#define TSTRIDE 33                    // row-epi transpose stride: 33%32==1 -> conflict-free

typedef __attribute__((ext_vector_type(8))) short bf16x8;
typedef __attribute__((ext_vector_type(16))) float f32x16;

static __device__ inline unsigned short f2bf(float f) {
    unsigned int u = __float_as_uint(f);
    return (unsigned short)((u + 0x7FFFu + ((u >> 16) & 1u)) >> 16);  // RNE
}
static __device__ inline bf16x8 bzero() {
    bf16x8 z;
    #pragma unroll
    for (int i = 0; i < 8; ++i) z[i] = 0;
    return z;
}
static __device__ inline f32x16 fzero16() {
    f32x16 z;
    #pragma unroll
    for (int i = 0; i < 16; ++i) z[i] = 0.f;
    return z;
}
static __device__ inline float min3f(float a, float b, float c) {
    return fminf(fminf(a, b), c);     // v_min3_f32
}
// min over one f32x16 via min3 tree: 8 ops.
static __device__ inline float tree16(const f32x16 x) {
    const float p0 = min3f(x[0], x[1], x[2]);
    const float p1 = min3f(x[3], x[4], x[5]);
    const float p2 = min3f(x[6], x[7], x[8]);
    const float p3 = min3f(x[9], x[10], x[11]);
    const float p4 = min3f(x[12], x[13], x[14]);
    const float q0 = min3f(p0, p1, x[15]);
    const float q1 = min3f(p2, p3, p4);
    return fminf(q0, q1);
}

#define MFMA32(Af, Bf, Cf) __builtin_amdgcn_mfma_f32_32x32x16_bf16(Af, Bf, Cf, 0, 0, 0)

// ---------------------------------------------------------------------------
// Chamfer (R13 structure, proven 27.1us): ONE distance matrix, BOTH
// reductions. 512-thread blocks, 8 waves x 1 A-frag (32 rows) -> 4 waves/SIMD.
// Col partials in per-wave bf16-pair planes (plain writes). Row-epilogue
// transpose stride fixed 36 -> 33 (R15 PMC showed 131072 LDS bank conflicts
// from the stride-36 8-way pattern; 33 % 32 == 1 -> 2-way, free).
// ---------------------------------------------------------------------------
__global__ __launch_bounds__(512, 4) void chamfer_min_kernel(
    const float* __restrict__ pred, const float* __restrict__ gt,
    float* __restrict__ ws, float* __restrict__ out)
{
    const int bx  = blockIdx.x;
    const int tid = threadIdx.x;
    if (bx == 0 && tid == 0) *out = 0.0f;

    __shared__ __align__(16) unsigned char lds[65536];
    uint4* sB = (uint4*)lds;                          // [0, 32768)
    const bf16x8* sBf = (const bf16x8*)lds;
    unsigned* colw = (unsigned*)(lds + 32768);        // [32768, 65536): 8 x 1024 u32
    float* epi = (float*)lds;                         // row-epi reuse

    const int lane = tid & 63;
    const int w    = tid >> 6;                        // wave 0..7
    const int li   = lane & 31;
    const int hi   = lane >> 5;
    const int tile   = bx & 15;
    const int mslice = (bx >> 4) & 1;
    const int b      = bx >> 5;
    const float* rb = pred + (size_t)b * NN * 3;
    const float* cb = gt + ((size_t)b * MM + (size_t)mslice * SLICE_COLS) * 3;

    // A-frag: 32 rows (rbase+li). Lanes 0-31 carry k=0..7 (k0..4); 32-63 zero.
    const int rbase = tile * ROWS_PER_BLOCK + w * 32;
    bf16x8 A0 = bzero();
    if (lane < 32) {
        const float* rp = rb + (size_t)(rbase + li) * 3;
        const float px = rp[0], py = rp[1], pz = rp[2];
        const float p2 = px * px + py * py + pz * pz;
        bf16x8 fr = bzero();
        fr[0] = (short)f2bf(-2.f * px);
        fr[1] = (short)f2bf(-2.f * py);
        fr[2] = (short)f2bf(-2.f * pz);
        fr[3] = (short)f2bf(p2);
        fr[4] = (short)0x3F80;              // 1.0
        A0 = fr;
    }

    // Stage gt slice: packed bf16x8 per col = (t,1,t2,0,0,0). 2 col-pairs/thread.
    #pragma unroll
    for (int i = 0; i < 2; ++i) {
        const int c0 = (i * 512 + tid) * 2;
        const float2* sp = (const float2*)(cb + (size_t)c0 * 3);
        const float2 v0 = sp[0], v1 = sp[1], v2 = sp[2];
        const float t2a = v0.x * v0.x + v0.y * v0.y + v1.x * v1.x;
        const float t2b = v1.y * v1.y + v2.x * v2.x + v2.y * v2.y;
        uint4 pa, pb;
        pa.x = (unsigned)f2bf(v0.x) | ((unsigned)f2bf(v0.y) << 16);
        pa.y = (unsigned)f2bf(v1.x) | (0x3F80u << 16);
        pa.z = (unsigned)f2bf(t2a);
        pa.w = 0u;
        pb.x = (unsigned)f2bf(v1.y) | ((unsigned)f2bf(v2.x) << 16);
        pb.y = (unsigned)f2bf(v2.y) | (0x3F80u << 16);
        pb.z = (unsigned)f2bf(t2b);
        pb.w = 0u;
        sB[c0]     = pa;
        sB[c0 + 1] = pb;
    }
    __syncthreads();

    float mv[16];
    #pragma unroll
    for (int r = 0; r < 16; ++r) mv[r] = 3.4e38f;

    const f32x16 Z = fzero16();
    unsigned* myplane = colw + w * 1024;

    bf16x8 c1 = sBf[li], c2 = sBf[32 + li];   // lanes>=32 dup-read (A=0 there)
    #pragma unroll 2
    for (int jt = 0; jt < NJT; ++jt) {
        bf16x8 n1 = c1, n2 = c2;
        if (jt + 1 < NJT) {
            n1 = sBf[(jt + 1) * 64 + li];
            n2 = sBf[(jt + 1) * 64 + 32 + li];
        }
        f32x16 a0 = MFMA32(A0, c1, Z);        // col group li
        f32x16 a1 = MFMA32(A0, c2, Z);        // col group 32+li
        #pragma unroll
        for (int r = 0; r < 16; ++r)
            mv[r] = min3f(a0[r], a1[r], mv[r]);
        float tA = tree16(a0);
        float tB = tree16(a1);
        tA = fminf(tA, __shfl_xor(tA, 32, 64));
        tB = fminf(tB, __shfl_xor(tB, 32, 64));
        unsigned pk;
        asm("v_cvt_pk_bf16_f32 %0, %1, %2" : "=v"(pk) : "v"(tA), "v"(tB));
        if (lane < 32) myplane[jt * 32 + li] = pk;
        c1 = n1; c2 = n2;
    }
    __syncthreads();                          // colw complete

    // Col epilogue: umin across 8 planes per u16 half, coalesced u32 ws store.
    {
        unsigned* wc = (unsigned*)(ws + WSCOL_OFF)
                     + (((size_t)b * 16 + tile) * NSLICE + mslice) * 1024;
        #pragma unroll
        for (int i = 0; i < 2; ++i) {
            const int slot = i * 512 + tid;
            unsigned la = 0xFFFFu, ha = 0xFFFFu;
            #pragma unroll
            for (int p = 0; p < 8; ++p) {
                const unsigned u = colw[p * 1024 + slot];
                la = min(la, u & 0xFFFFu);
                ha = min(ha, u >> 16);
            }
            wc[slot] = la | (ha << 16);
        }
    }
    __syncthreads();                          // colw free; row transpose begins

    // Row epilogue: transpose mv via LDS [wave][col li][row_local], stride 33.
    {
        float* wb = epi + w * 1152 + li * TSTRIDE;
        #pragma unroll
        for (int q = 0; q < 4; ++q)
            *(float4*)&wb[q * 8 + hi * 4] =
                make_float4(mv[4*q], mv[4*q+1], mv[4*q+2], mv[4*q+3]);
    }
    __syncthreads();

    if (tid < ROWS_PER_BLOCK) {
        const int wsrc = tid >> 5, rl = tid & 31;
        const float* rr = epi + wsrc * 1152 + rl;
        float m = 3.4e38f;
        #pragma unroll
        for (int c = 0; c < 32; c += 2)
            m = min3f(rr[c * TSTRIDE], rr[(c + 1) * TSTRIDE], m);
        ws[((size_t)b * NSLICE + mslice) * NN + tile * ROWS_PER_BLOCK + tid] = m;
    }
}

// ---------------------------------------------------------------------------
// Finish (+reg), 48 blocks:
//   [0,16):  rows for b — min over 2 slices, sqrt, sum.
//   [16,32): cols for b — u16-min over 16 tile planes, decode bf16, sqrt, sum.
//   [32,48): regularizer via MFMA.
// ---------------------------------------------------------------------------
__global__ __launch_bounds__(256) void finish_reg_kernel(
    const float* __restrict__ ws, const float* __restrict__ trans,
    float* __restrict__ out)
{
    const int bx  = blockIdx.x;
    const int tid = threadIdx.x;
    __shared__ float ssum[4];

    if (bx < BB) {
        // ------------------------ pred rows ------------------------
        const int b = bx;
        const float* p0 = ws + ((size_t)b * NSLICE) * NN;
        float s = 0.f;
        #pragma unroll 4
        for (int i = 0; i < NN / 256; ++i) {
            const int n = i * 256 + tid;
            const float v = fminf(p0[n], p0[NN + n]);
            s += sqrtf(fmaxf(v, 0.0f));
        }
        #pragma unroll
        for (int off = 32; off > 0; off >>= 1)
            s += __shfl_down(s, off, 64);
        if ((tid & 63) == 0) ssum[tid >> 6] = s;
        __syncthreads();
        if (tid == 0)
            atomicAdd(out, (ssum[0] + ssum[1] + ssum[2] + ssum[3])
                               * (1.0f / ((float)BB * (float)NN)));
        return;
    }
    if (bx < 2 * BB) {
        // ------------------------- gt cols -------------------------
        const int b = bx - BB;
        const unsigned* base = (const unsigned*)(ws + WSCOL_OFF)
                             + (size_t)b * 16 * NSLICE * 1024;
        float s = 0.f;
        #pragma unroll
        for (int i = 0; i < 8; ++i) {
            const int idx = i * 256 + tid;          // 0..2047
            const int sl  = idx >> 10;              // slice
            const int slot = idx & 1023;
            unsigned la = 0xFFFFu, ha = 0xFFFFu;
            #pragma unroll
            for (int t = 0; t < 16; ++t) {
                const unsigned u = base[((size_t)t * NSLICE + sl) * 1024 + slot];
                la = min(la, u & 0xFFFFu);
                ha = min(ha, u >> 16);
            }
            s += sqrtf(fmaxf(__uint_as_float(la << 16), 0.0f));
            s += sqrtf(fmaxf(__uint_as_float(ha << 16), 0.0f));
        }
        #pragma unroll
        for (int off = 32; off > 0; off >>= 1)
            s += __shfl_down(s, off, 64);
        if ((tid & 63) == 0) ssum[tid >> 6] = s;
        __syncthreads();
        if (tid == 0)
            atomicAdd(out, (ssum[0] + ssum[1] + ssum[2] + ssum[3])
                               * (1.0f / ((float)BB * (float)NN)));
        return;
    }

    // ------------------------- regularizer -------------------------
    if (tid < 64) {
        const int b = bx - 2 * BB;
        const int lane = tid;
        const int hi = lane >> 5, li = lane & 31;
        const float* T = trans + (size_t)b * 64 * 64;
        bf16x8 frag[2][4];
        #pragma unroll
        for (int h = 0; h < 2; ++h)
            #pragma unroll
            for (int s = 0; s < 4; ++s) {
                const float* rp = T + (size_t)(h * 32 + li) * 64 + s * 16 + hi * 8;
                const float4 u0 = *(const float4*)rp;
                const float4 u1 = *(const float4*)(rp + 4);
                bf16x8 fr;
                fr[0] = (short)f2bf(u0.x); fr[1] = (short)f2bf(u0.y);
                fr[2] = (short)f2bf(u0.z); fr[3] = (short)f2bf(u0.w);
                fr[4] = (short)f2bf(u1.x); fr[5] = (short)f2bf(u1.y);
                fr[6] = (short)f2bf(u1.z); fr[7] = (short)f2bf(u1.w);
                frag[h][s] = fr;
            }
        float fsum = 0.f;
        #pragma unroll
        for (int fi = 0; fi < 2; ++fi)
            #pragma unroll
            for (int fj = 0; fj < 2; ++fj) {
                f32x16 a = fzero16();
                #pragma unroll
                for (int s = 0; s < 4; ++s)
                    a = MFMA32(frag[fi][s], frag[fj][s], a);
                #pragma unroll
                for (int r = 0; r < 16; ++r) {
                    const int row = fi * 32 + (r & 3) + 8 * (r >> 2) + 4 * hi;
                    const int col = fj * 32 + li;
                    const float d = a[r] - ((row == col) ? 1.0f : 0.0f);
                    fsum = fmaf(d, d, fsum);
                }
            }
        #pragma unroll
        for (int off = 32; off > 0; off >>= 1)
            fsum += __shfl_down(fsum, off, 64);
        if (lane == 0)
            atomicAdd(out, (0.1f / (float)BB) * sqrtf(fsum));
    }
}

extern "C" void kernel_launch(void* const* d_in, const int* in_sizes, int n_in,
                              void* d_out, int out_size, void* d_ws, size_t ws_size,
                              hipStream_t stream)
{
    const float* pred  = (const float*)d_in[0];
    const float* gt    = (const float*)d_in[1];
    const float* trans = (const float*)d_in[2];
    float* out = (float*)d_out;
    float* ws = (float*)d_ws;

    chamfer_min_kernel<<<dim3(NCHAMFER), dim3(512), 0, stream>>>(pred, gt, ws, out);
    finish_reg_kernel<<<dim3(3 * BB), dim3(256), 0, stream>>>(ws, trans, out);
}